// Round 2
// baseline (128.031 us; speedup 1.0000x reference)
//
#include <hip/hip_runtime.h>
#include <math.h>

#define SEQ 100
#define BATCH 256
#define NREP 8
#define FFDIM 2048

// ---------------------------------------------------------------- helpers
__device__ __forceinline__ float wave_sum64(float v) {
    #pragma unroll
    for (int o = 32; o > 0; o >>= 1) v += __shfl_xor(v, o, 64);
    return v;
}

// ---------------------------------------------------------------- stage A
// h = x*cw+cb; 8x { h = gelu(LN_[100,4](h@Wl.T+bl)*g+b) }; X = h@Wl.T+bl
// one block per batch element; thread r (<100) owns row r (4 floats in regs)
__global__ __launch_bounds__(128) void k_stageA(
    const float* __restrict__ x, const float* __restrict__ convw,
    const float* __restrict__ convb, const float* __restrict__ Wl,
    const float* __restrict__ bl, const float* __restrict__ lng,
    const float* __restrict__ lnb, float* __restrict__ X)
{
    const int b = blockIdx.x;
    const int r = threadIdx.x;
    const bool act = (r < SEQ);
    __shared__ float red[2][2];

    const float cw = convw[0], cb = convb[0];
    float W[4][4], B[4];
    #pragma unroll
    for (int j = 0; j < 4; ++j) {
        B[j] = bl[j];
        #pragma unroll
        for (int d = 0; d < 4; ++d) W[j][d] = Wl[j * 4 + d];
    }

    float h[4] = {0.f, 0.f, 0.f, 0.f};
    float g4[4] = {0.f, 0.f, 0.f, 0.f}, b4[4] = {0.f, 0.f, 0.f, 0.f};
    if (act) {
        float4 xr = *(const float4*)(x + (b * SEQ + r) * 4);
        h[0] = fmaf(xr.x, cw, cb); h[1] = fmaf(xr.y, cw, cb);
        h[2] = fmaf(xr.z, cw, cb); h[3] = fmaf(xr.w, cw, cb);
        float4 g = *(const float4*)(lng + r * 4);
        float4 bb = *(const float4*)(lnb + r * 4);
        g4[0] = g.x; g4[1] = g.y; g4[2] = g.z; g4[3] = g.w;
        b4[0] = bb.x; b4[1] = bb.y; b4[2] = bb.z; b4[3] = bb.w;
    }

    for (int it = 0; it < NREP; ++it) {
        float y[4] = {0.f, 0.f, 0.f, 0.f};
        float s1 = 0.f, s2 = 0.f;
        if (act) {
            #pragma unroll
            for (int j = 0; j < 4; ++j) {
                float yy = B[j];
                #pragma unroll
                for (int d = 0; d < 4; ++d) yy = fmaf(h[d], W[j][d], yy);
                y[j] = yy; s1 += yy; s2 = fmaf(yy, yy, s2);
            }
        }
        s1 = wave_sum64(s1);
        s2 = wave_sum64(s2);
        const int wid = threadIdx.x >> 6;
        if ((threadIdx.x & 63) == 0) { red[wid][0] = s1; red[wid][1] = s2; }
        __syncthreads();
        const float tS = red[0][0] + red[1][0];
        const float tQ = red[0][1] + red[1][1];
        __syncthreads();
        const float mean = tS * (1.0f / 400.0f);
        const float var  = tQ * (1.0f / 400.0f) - mean * mean;
        const float rstd = rsqrtf(var + 1e-5f);
        if (act) {
            #pragma unroll
            for (int j = 0; j < 4; ++j) {
                float v = fmaf((y[j] - mean) * rstd, g4[j], b4[j]);
                h[j] = 0.5f * v * (1.0f + erff(v * 0.70710678118654752f));
            }
        }
    }
    if (act) {
        float y[4];
        #pragma unroll
        for (int j = 0; j < 4; ++j) {
            float yy = B[j];
            #pragma unroll
            for (int d = 0; d < 4; ++d) yy = fmaf(h[d], W[j][d], yy);
            y[j] = yy;
        }
        *(float4*)(X + (b * SEQ + r) * 4) = make_float4(y[0], y[1], y[2], y[3]);
    }
}

// ---------------------------------------------------------------- attention
// block = (n, head); thread = s (0..255). qkv per head, k/v staged in LDS,
// exact row-max via q*kmax / q*kmin trick, online num/den accumulation.
__global__ __launch_bounds__(256) void k_attn(
    const float* __restrict__ X, float* __restrict__ O,
    const float* __restrict__ Win, const float* __restrict__ bi)
{
    const int n  = blockIdx.x;   // 0..99
    const int hd = blockIdx.y;   // 0..3
    const int s  = threadIdx.x;  // 0..255
    __shared__ float2 kv[256];
    __shared__ float red[4][2];

    float4 xr = *(const float4*)(X + (s * SEQ + n) * 4);
    const float* wq = Win + hd * 4;
    const float* wk = Win + (4 + hd) * 4;
    const float* wv = Win + (8 + hd) * 4;
    float q = bi[hd]     + xr.x*wq[0] + xr.y*wq[1] + xr.z*wq[2] + xr.w*wq[3];
    float k = bi[4 + hd] + xr.x*wk[0] + xr.y*wk[1] + xr.z*wk[2] + xr.w*wk[3];
    float v = bi[8 + hd] + xr.x*wv[0] + xr.y*wv[1] + xr.z*wv[2] + xr.w*wv[3];
    kv[s] = make_float2(k, v);

    float kmx = k, kmn = k;
    #pragma unroll
    for (int o = 32; o > 0; o >>= 1) {
        kmx = fmaxf(kmx, __shfl_xor(kmx, o, 64));
        kmn = fminf(kmn, __shfl_xor(kmn, o, 64));
    }
    const int wid = s >> 6;
    if ((s & 63) == 0) { red[wid][0] = kmx; red[wid][1] = kmn; }
    __syncthreads();
    kmx = fmaxf(fmaxf(red[0][0], red[1][0]), fmaxf(red[2][0], red[3][0]));
    kmn = fminf(fminf(red[0][1], red[1][1]), fminf(red[2][1], red[3][1]));

    const float m = (q >= 0.f) ? q * kmx : q * kmn;   // exact max_t(q*k_t)
    float den = 0.f, num = 0.f;
    #pragma unroll 8
    for (int t = 0; t < 256; ++t) {
        float2 kvt = kv[t];
        float p = __expf(fmaf(q, kvt.x, -m));
        den += p;
        num = fmaf(p, kvt.y, num);
    }
    O[(s * SEQ + n) * 4 + hd] = num / den;
}

// ---------------------------------------------------------------- proj+LN1+FFN+LN2
// block = 64 rows x 16 waves. wave 0 does proj/residual/LN1 into LDS;
// then each (wave w, lane r) handles row r, f-chunk [w*128,(w+1)*128) with
// wave-uniform (scalar) weight loads; LDS partial-acc reduce; LN2 via shfl.
__global__ __launch_bounds__(1024) void k_ffn(
    float* __restrict__ X, const float* __restrict__ O,
    const float* __restrict__ Wout, const float* __restrict__ bout,
    const float* __restrict__ W1, const float* __restrict__ b1,
    const float* __restrict__ W2, const float* __restrict__ b2,
    const float* __restrict__ g1, const float* __restrict__ be1,
    const float* __restrict__ g2, const float* __restrict__ be2)
{
    __shared__ float x1s[64][4];
    __shared__ float pacc[16][64][4];
    const int wid  = threadIdx.x >> 6;
    const int lane = threadIdx.x & 63;

    if (wid == 0) {
        const int g = blockIdx.x * 64 + lane;
        float4 xr = *(const float4*)(X + g * 4);
        float4 orow = *(const float4*)(O + g * 4);
        float xv[4] = {xr.x, xr.y, xr.z, xr.w};
        float ov[4] = {orow.x, orow.y, orow.z, orow.w};
        float rr[4];
        #pragma unroll
        for (int d = 0; d < 4; ++d) {
            float op = bout[d];
            #pragma unroll
            for (int e = 0; e < 4; ++e) op = fmaf(ov[e], Wout[d * 4 + e], op);
            rr[d] = xv[d] + op;
        }
        float mean = 0.25f * (rr[0] + rr[1] + rr[2] + rr[3]);
        float var = 0.f;
        #pragma unroll
        for (int d = 0; d < 4; ++d) { float dv = rr[d] - mean; var = fmaf(dv, dv, var); }
        float rstd = rsqrtf(0.25f * var + 1e-5f);
        #pragma unroll
        for (int d = 0; d < 4; ++d)
            x1s[lane][d] = fmaf((rr[d] - mean) * rstd, g1[d], be1[d]);
    }
    __syncthreads();

    const float x0 = x1s[lane][0], x1_ = x1s[lane][1];
    const float x2_ = x1s[lane][2], x3_ = x1s[lane][3];
    float a0 = 0.f, a1 = 0.f, a2 = 0.f, a3 = 0.f;
    const int fbase = __builtin_amdgcn_readfirstlane(wid) * 128;
    #pragma unroll 4
    for (int j = 0; j < 128; ++j) {
        const int f = fbase + j;
        const float w0 = W1[f * 4 + 0], w1 = W1[f * 4 + 1];
        const float w2 = W1[f * 4 + 2], w3 = W1[f * 4 + 3];
        float hh = b1[f];
        hh = fmaf(x0, w0, hh); hh = fmaf(x1_, w1, hh);
        hh = fmaf(x2_, w2, hh); hh = fmaf(x3_, w3, hh);
        hh = fmaxf(hh, 0.f);
        a0 = fmaf(hh, W2[0 * FFDIM + f], a0);
        a1 = fmaf(hh, W2[1 * FFDIM + f], a1);
        a2 = fmaf(hh, W2[2 * FFDIM + f], a2);
        a3 = fmaf(hh, W2[3 * FFDIM + f], a3);
    }
    pacc[wid][lane][0] = a0; pacc[wid][lane][1] = a1;
    pacc[wid][lane][2] = a2; pacc[wid][lane][3] = a3;
    __syncthreads();

    if (threadIdx.x < 256) {
        const int r = threadIdx.x >> 2, d = threadIdx.x & 3;
        float s = b2[d];
        #pragma unroll
        for (int w = 0; w < 16; ++w) s += pacc[w][r][d];
        float val = x1s[r][d] + s;
        float sum = val + __shfl_xor(val, 1, 64);
        sum += __shfl_xor(sum, 2, 64);
        const float mean = 0.25f * sum;
        const float dv = val - mean;
        float qq = dv * dv;
        float qs = qq + __shfl_xor(qq, 1, 64);
        qs += __shfl_xor(qs, 2, 64);
        const float rstd = rsqrtf(0.25f * qs + 1e-5f);
        X[(blockIdx.x * 64 + r) * 4 + d] = fmaf(dv * rstd, g2[d], be2[d]);
    }
}

// ---------------------------------------------------------------- final
__global__ __launch_bounds__(256) void k_final(
    const float* __restrict__ X, const float* __restrict__ Wl,
    const float* __restrict__ bl, float* __restrict__ out)
{
    const int g = blockIdx.x * 256 + threadIdx.x; // < 25600
    float4 xr = *(const float4*)(X + g * 4);
    float xv[4] = {xr.x, xr.y, xr.z, xr.w};
    float y[4];
    #pragma unroll
    for (int j = 0; j < 4; ++j) {
        float yy = bl[j];
        #pragma unroll
        for (int d = 0; d < 4; ++d) yy = fmaf(xv[d], Wl[j * 4 + d], yy);
        y[j] = yy;
    }
    float m = fmaxf(fmaxf(y[0], y[1]), fmaxf(y[2], y[3]));
    float e[4], s = 0.f;
    #pragma unroll
    for (int j = 0; j < 4; ++j) { e[j] = __expf(y[j] - m); s += e[j]; }
    const float inv = 1.0f / s;
    *(float4*)(out + g * 4) =
        make_float4(e[0] * inv, e[1] * inv, e[2] * inv, e[3] * inv);
}

// ---------------------------------------------------------------- launch
extern "C" void kernel_launch(void* const* d_in, const int* in_sizes, int n_in,
                              void* d_out, int out_size, void* d_ws, size_t ws_size,
                              hipStream_t stream)
{
    const float* x     = (const float*)d_in[0];
    const float* convw = (const float*)d_in[1];
    const float* convb = (const float*)d_in[2];
    const float* Wl    = (const float*)d_in[3];
    const float* bl    = (const float*)d_in[4];
    const float* lng   = (const float*)d_in[5];
    const float* lnb   = (const float*)d_in[6];
    const float* Win   = (const float*)d_in[7];
    const float* bi    = (const float*)d_in[8];
    const float* Wout  = (const float*)d_in[9];
    const float* bout  = (const float*)d_in[10];
    const float* W1    = (const float*)d_in[11];
    const float* b1    = (const float*)d_in[12];
    const float* W2    = (const float*)d_in[13];
    const float* b2    = (const float*)d_in[14];
    const float* g1    = (const float*)d_in[15];
    const float* be1   = (const float*)d_in[16];
    const float* g2    = (const float*)d_in[17];
    const float* be2   = (const float*)d_in[18];

    float* X = (float*)d_ws;            // [256*100*4]
    float* O = X + BATCH * SEQ * 4;     // [256*100*4]
    float* out = (float*)d_out;

    k_stageA<<<BATCH, 128, 0, stream>>>(x, convw, convb, Wl, bl, lng, lnb, X);
    for (int l = 0; l < 4; ++l) {
        k_attn<<<dim3(SEQ, 4), 256, 0, stream>>>(X, O, Win + l * 48, bi + l * 12);
        k_ffn<<<400, 1024, 0, stream>>>(X, O,
            Wout + l * 16, bout + l * 4,
            W1 + l * FFDIM * 4, b1 + l * FFDIM,
            W2 + l * 4 * FFDIM, b2 + l * 4,
            g1 + l * 4, be1 + l * 4, g2 + l * 4, be2 + l * 4);
    }
    k_final<<<SEQ, 256, 0, stream>>>(X, Wl, bl, out);
}